// Round 8
// baseline (424.865 us; speedup 1.0000x reference)
//
#include <hip/hip_runtime.h>

// Inputs/outputs FLOAT32 per the reference. bf16 internally for MFMA (raw u16).
// r15: r14 + the missing latency hiding. r14 (F direct-from-global) halved LDS
// traffic and conflicts as predicted, but got SLOWER (97->160us, MfmaUtil 15):
// its F loads issue after the barrier and are consumed immediately -> raw
// global latency exposed every K-step (T14 violation). r15 keeps F in regs but
// PREFETCHES one K-step ahead (issued right after the weight-DMA for k+1);
// the barrier's implicit vmcnt(0) makes them ready at each step's top, same
// as r8's DMA'd F. Manual unroll-by-2 ping-pongs two F register sets (static
// indexing only). LDS = weights hi/lo only (32KB dbuf). Math bit-identical.
typedef unsigned short u16;
typedef unsigned int u32;
typedef __attribute__((ext_vector_type(8))) short short8;   // MFMA A/B frag
typedef __attribute__((ext_vector_type(4))) float f32x4;    // MFMA C/D frag

__device__ inline u16 f32_to_bf16(float f) {          // RNE (cold paths only)
  u32 u = __float_as_uint(f);
  u += 0x7fffu + ((u >> 16) & 1u);
  return (u16)(u >> 16);
}
__device__ inline float bf16_to_f32(u16 s) {
  return __uint_as_float(((u32)s) << 16);
}

#if __has_builtin(__builtin_amdgcn_exp2f)
#define EXP2F(x) __builtin_amdgcn_exp2f(x)
#else
#define EXP2F(x) exp2f(x)
#endif

// async 16B global->LDS DMA (dest = wave-uniform LDS base + lane*16)
__device__ inline void dma16(const void* gp, void* lp) {
  __builtin_amdgcn_global_load_lds(
      (const __attribute__((address_space(1))) u32*)gp,
      (__attribute__((address_space(3))) u32*)lp, 16, 0, 0);
}

// pack top-16 of two f32 words: out = (hi16(b)<<16) | hi16(a)
__device__ inline u32 pack_hi16(u32 a, u32 b) {
  return __builtin_amdgcn_perm(b, a, 0x07060302u);
}
// 8 f32 -> bf16x8 via truncation
__device__ inline uint4 pack_bf16_8(const uint4 a, const uint4 b) {
  uint4 r;
  r.x = pack_hi16(a.x, a.y);
  r.y = pack_hi16(a.z, a.w);
  r.z = pack_hi16(b.x, b.y);
  r.w = pack_hi16(b.z, b.w);
  return r;
}
// 8 f32 -> hi/lo bf16 planes. hi=trunc; lo=trunc(v-hi) (v-hi exact, Sterbenz).
__device__ inline void split8(const uint4 a, const uint4 b, uint4& hi, uint4& lo) {
  u32 u[8] = {a.x, a.y, a.z, a.w, b.x, b.y, b.z, b.w};
  u32 l[8];
#pragma unroll
  for (int j = 0; j < 8; ++j)
    l[j] = __float_as_uint(__uint_as_float(u[j]) - __uint_as_float(u[j] & 0xffff0000u));
  hi.x = pack_hi16(u[0], u[1]); hi.y = pack_hi16(u[2], u[3]);
  hi.z = pack_hi16(u[4], u[5]); hi.w = pack_hi16(u[6], u[7]);
  lo.x = pack_hi16(l[0], l[1]); lo.y = pack_hi16(l[2], l[3]);
  lo.z = pack_hi16(l[4], l[5]); lo.w = pack_hi16(l[6], l[7]);
}

// ---------------------------------------------------------------------------
// Weight repack + f32 -> bf16 hi/lo planes (RNE; one-time). j = d*48 + k*16 + h.
__global__ void repack_w(const float* __restrict__ Wqkv, const float* __restrict__ Wtqkv,
                         const float* __restrict__ Wout,
                         u16* __restrict__ Wtq_hi, u16* __restrict__ Wtq_lo,
                         u16* __restrict__ Wk_hi,  u16* __restrict__ Wk_lo,
                         u16* __restrict__ Wv_hi,  u16* __restrict__ Woutb) {
  int r = blockIdx.x;              // 0..4095
  int part = r >> 10;
  int rr = r & 1023;
  int h = rr >> 6, d = rr & 63;
  const float* src;
  u16 *dh, *dl = nullptr;
  if (part == 0)      { src = Wtqkv + (size_t)(d * 48 + h) * 1024;      dh = Wtq_hi + (size_t)rr * 1024; dl = Wtq_lo + (size_t)rr * 1024; }
  else if (part == 1) { src = Wqkv  + (size_t)(d * 48 + 16 + h) * 1024; dh = Wk_hi  + (size_t)rr * 1024; dl = Wk_lo  + (size_t)rr * 1024; }
  else if (part == 2) { src = Wqkv  + (size_t)(d * 48 + 32 + h) * 1024; dh = Wv_hi  + (size_t)rr * 1024; }
  else                { src = Wout  + (size_t)rr * 1024;                dh = Woutb  + (size_t)rr * 1024; }
  int c = threadIdx.x * 4;
  f32x4 v = *(const f32x4*)&src[c];
  u32 hv[4], lv[4];
#pragma unroll
  for (int j = 0; j < 4; ++j) {
    u16 hb = f32_to_bf16(v[j]);
    hv[j] = hb;
    lv[j] = f32_to_bf16(v[j] - bf16_to_f32(hb));
  }
  uint2 ho; ho.x = hv[0] | (hv[1] << 16); ho.y = hv[2] | (hv[3] << 16);
  *(uint2*)&dh[c] = ho;
  if (dl) {
    uint2 lo; lo.x = lv[0] | (lv[1] << 16); lo.y = lv[2] | (lv[3] << 16);
    *(uint2*)&dl[c] = lo;
  }
}

// ---------------------------------------------------------------------------
// Fused projection GEMM v6: 128x128 tile. Weights hi/lo via global_load_lds
// (32KB dbuf); f32 operand in REGISTERS, prefetched one K-step ahead.
// grid (256,3) = 768 blocks, 4 waves.
__global__ __launch_bounds__(256) __attribute__((amdgpu_waves_per_eu(2)))
void proj_fused(const float* __restrict__ x, const float* __restrict__ tx,
                const u16* __restrict__ Wtq_hi, const u16* __restrict__ Wtq_lo,
                const u16* __restrict__ Wk_hi,  const u16* __restrict__ Wk_lo,
                const u16* __restrict__ Wv_hi,
                u16* __restrict__ Qhi, u16* __restrict__ Qlo,
                u16* __restrict__ Khi, u16* __restrict__ Klo,
                u16* __restrict__ Vt, float qscale) {
  __shared__ __align__(16) u16 Hs[2][128][32];
  __shared__ __align__(16) u16 Ls[2][128][32];
  const int tid = threadIdx.x;
  const int wid = tid >> 6, lane = tid & 63;
  const int g = lane >> 4, l16 = lane & 15;
  const int job = blockIdx.y;
  const int tile = blockIdx.x;
  const int wm = (wid & 1) * 64, wn = (wid >> 1) * 64;

  int m0, n0, N, hrow0;
  const float* Fsrc;
  const u16 *Hsrc;
  const u16 *Lsrc = nullptr;
  if (job == 0) {
    m0 = (tile >> 3) * 128; n0 = (tile & 7) * 128; N = 1024;
    Fsrc = tx; Hsrc = Wtq_hi; Lsrc = Wtq_lo; hrow0 = n0;
  } else if (job == 1) {
    m0 = (tile >> 3) * 128; n0 = (tile & 7) * 128; N = 1024;
    Fsrc = x; Hsrc = Wk_hi; Lsrc = Wk_lo; hrow0 = n0;
  } else {
    m0 = (tile >> 5) * 128; n0 = (tile & 31) * 128; N = 4096;
    Fsrc = x; Hsrc = Wv_hi; hrow0 = m0;
  }

  // f32-operand row base: jobs 0/1 -> A rows (m side), job 2 -> B rows (n).
  const int frow = (job != 2) ? (m0 + wm) : (n0 + wn);

  // H/L DMA lane geometry: 4x16B granules per 64B row, gran ^= (r^(r>>2))&3.
  const int lrow4 = lane >> 2;
  const int gh = (lane & 3) ^ ((lrow4 ^ (lrow4 >> 2)) & 3);

  auto issue_chunk = [&](int k0, int p) {
#pragma unroll
    for (int t = 0; t < 2; ++t) {            // H/L: 128 rows, 16 rows/dma
      int rb = wid * 32 + t * 16;
      size_t ro = (size_t)(hrow0 + rb + lrow4) * 1024 + k0 + gh * 8;
      dma16(&Hsrc[ro], &Hs[p][rb][0]);
      if (job != 2) dma16(&Lsrc[ro], &Ls[p][rb][0]);
    }
  };

  // dense 32B/lane f32 fragment loads for step k0 (L1/L2-resident panel)
  auto loadF = [&](int k0, uint4 (&a0)[4], uint4 (&a1)[4]) {
#pragma unroll
    for (int i = 0; i < 4; ++i) {
      const float* fp = &Fsrc[(size_t)(frow + i * 16 + l16) * 1024 + k0 + g * 8];
      a0[i] = *(const uint4*)fp;
      a1[i] = *(const uint4*)(fp + 4);
    }
  };

  f32x4 acc[4][4];
  const f32x4 zero4 = {0.f, 0.f, 0.f, 0.f};
#pragma unroll
  for (int i = 0; i < 4; ++i)
#pragma unroll
    for (int j = 0; j < 4; ++j) acc[i][j] = zero4;

  const int sw4 = (l16 ^ (l16 >> 2)) & 3;    // H/L read-side swizzle

  // one K-step: compute from (c0,c1); prefetch k0+32 into (n0_,n1_)
  auto kstep = [&](int k0, uint4 (&c0)[4], uint4 (&c1)[4],
                   uint4 (&n0_)[4], uint4 (&n1_)[4]) {
    const int p = (k0 >> 5) & 1;
    // Barrier's implicit vmcnt(0): weight DMA into buf p AND the F register
    // prefetch for this step (both issued last iter) are complete.
    __syncthreads();
    if (k0 + 32 < 1024) {
      issue_chunk(k0 + 32, p ^ 1);
      loadF(k0 + 32, n0_, n1_);
    }

    if (job != 2) {
      short8 ah[4], al[4], bh4[4], bl4[4];
#pragma unroll
      for (int mi = 0; mi < 4; ++mi) {
        uint4 hi, lo;
        split8(c0[mi], c1[mi], hi, lo);
        ah[mi] = *(short8*)&hi;
        al[mi] = *(short8*)&lo;
      }
#pragma unroll
      for (int ni = 0; ni < 4; ++ni) {
        const int R = wn + ni * 16 + l16;
        bh4[ni] = *(const short8*)&Hs[p][R][(g ^ sw4) * 8];
        bl4[ni] = *(const short8*)&Ls[p][R][(g ^ sw4) * 8];
      }
#pragma unroll
      for (int mi = 0; mi < 4; ++mi)
#pragma unroll
        for (int ni = 0; ni < 4; ++ni) {
          acc[mi][ni] = __builtin_amdgcn_mfma_f32_16x16x32_bf16(ah[mi], bh4[ni], acc[mi][ni], 0, 0, 0);
          acc[mi][ni] = __builtin_amdgcn_mfma_f32_16x16x32_bf16(ah[mi], bl4[ni], acc[mi][ni], 0, 0, 0);
          acc[mi][ni] = __builtin_amdgcn_mfma_f32_16x16x32_bf16(al[mi], bh4[ni], acc[mi][ni], 0, 0, 0);
        }
    } else {
      short8 av[4], bx[4];
#pragma unroll
      for (int mi = 0; mi < 4; ++mi)
        av[mi] = *(const short8*)&Hs[p][wm + mi * 16 + l16][(g ^ sw4) * 8];
#pragma unroll
      for (int ni = 0; ni < 4; ++ni) {
        uint4 t = pack_bf16_8(c0[ni], c1[ni]);
        bx[ni] = *(short8*)&t;
      }
#pragma unroll
      for (int mi = 0; mi < 4; ++mi)
#pragma unroll
        for (int ni = 0; ni < 4; ++ni)
          acc[mi][ni] = __builtin_amdgcn_mfma_f32_16x16x32_bf16(av[mi], bx[ni], acc[mi][ni], 0, 0, 0);
    }
  };

  uint4 A0[4], A1[4], B0[4], B1[4];
  issue_chunk(0, 0);
  loadF(0, A0, A1);

  // 32 steps, manually unrolled by 2 so the F register buffers ping-pong
  // with compile-time-static indexing (no scratch).
  for (int k0 = 0; k0 < 1024; k0 += 64) {
    kstep(k0,      A0, A1, B0, B1);
    kstep(k0 + 32, B0, B1, A0, A1);
  }

  u16* Chi = (job == 0) ? Qhi : ((job == 1) ? Khi : Vt);
  u16* Clo = (job == 0) ? Qlo : Klo;
  float scale = (job == 0) ? qscale : 1.0f;
#pragma unroll
  for (int mi = 0; mi < 4; ++mi)
#pragma unroll
    for (int ni = 0; ni < 4; ++ni) {
      int row = m0 + wm + mi * 16 + g * 4;
      int col = n0 + wn + ni * 16 + l16;
#pragma unroll
      for (int r = 0; r < 4; ++r) {
        float v = acc[mi][ni][r] * scale;
        size_t o = (size_t)(row + r) * N + col;
        u32 uv = __float_as_uint(v);
        if (job != 2) {
          Chi[o] = (u16)(uv >> 16);
          float lo = v - __uint_as_float(uv & 0xffff0000u);
          Clo[o] = (u16)(__float_as_uint(lo) >> 16);
        } else {
          Chi[o] = (u16)(uv >> 16);
        }
      }
    }
}

// ---------------------------------------------------------------------------
// Final projection (unchanged): C(f32) = A bf16 * B^T bf16.
__global__ __launch_bounds__(256) __attribute__((amdgpu_waves_per_eu(2, 4)))
void gemm_out(const u16* __restrict__ A, const u16* __restrict__ B,
              float* __restrict__ C, int M, int N, int K) {
  __shared__ __align__(16) u16 As[128][40];
  __shared__ __align__(16) u16 Bs[64][40];
  const int tid = threadIdx.x;
  const int wid = tid >> 6, lane = tid & 63;
  const int g = lane >> 4, l16 = lane & 15;
  const int m0 = blockIdx.y * 128, n0 = blockIdx.x * 64;
  const int wm = (wid & 1) * 64, wn = (wid >> 1) * 32;

  f32x4 acc[4][2];
  const f32x4 zero4 = {0.f, 0.f, 0.f, 0.f};
#pragma unroll
  for (int i = 0; i < 4; ++i)
#pragma unroll
    for (int j = 0; j < 2; ++j) acc[i][j] = zero4;

  uint4 pa[2], pb;
  const int rowA0 = tid >> 2, colA = (tid & 3) * 8;
  const int rowA1 = rowA0 + 64;
  const int rowB = tid >> 2, colB = (tid & 3) * 8;
  pa[0] = *(const uint4*)&A[(size_t)(m0 + rowA0) * K + colA];
  pa[1] = *(const uint4*)&A[(size_t)(m0 + rowA1) * K + colA];
  pb    = *(const uint4*)&B[(size_t)(n0 + rowB) * K + colB];

  for (int k0 = 0; k0 < K; k0 += 32) {
    __syncthreads();
    *(uint4*)&As[rowA0][colA] = pa[0];
    *(uint4*)&As[rowA1][colA] = pa[1];
    *(uint4*)&Bs[rowB][colB] = pb;
    __syncthreads();
    if (k0 + 32 < K) {
      pa[0] = *(const uint4*)&A[(size_t)(m0 + rowA0) * K + k0 + 32 + colA];
      pa[1] = *(const uint4*)&A[(size_t)(m0 + rowA1) * K + k0 + 32 + colA];
      pb    = *(const uint4*)&B[(size_t)(n0 + rowB) * K + k0 + 32 + colB];
    }
    short8 af[4], bfr[2];
#pragma unroll
    for (int mi = 0; mi < 4; ++mi)
      af[mi] = *(const short8*)&As[wm + mi * 16 + l16][g * 8];
#pragma unroll
    for (int ni = 0; ni < 2; ++ni)
      bfr[ni] = *(const short8*)&Bs[wn + ni * 16 + l16][g * 8];
#pragma unroll
    for (int mi = 0; mi < 4; ++mi)
#pragma unroll
      for (int ni = 0; ni < 2; ++ni)
        acc[mi][ni] = __builtin_amdgcn_mfma_f32_16x16x32_bf16(af[mi], bfr[ni], acc[mi][ni], 0, 0, 0);
  }
#pragma unroll
  for (int mi = 0; mi < 4; ++mi)
#pragma unroll
    for (int ni = 0; ni < 2; ++ni) {
      int row = m0 + wm + mi * 16 + g * 4;
      int col = n0 + wn + ni * 16 + l16;
#pragma unroll
      for (int r = 0; r < 4; ++r)
        C[(size_t)(row + r) * N + col] = acc[mi][ni][r];
    }
}

// ---------------------------------------------------------------------------
// Flash attention v10 (unchanged from r11): 8 waves x 16 q rows, swapped QK^T,
// in-register softmax with defer-max, __shfl P^T redistribution, PV = V^T.P^T.
__global__ __launch_bounds__(512)
void attn_fwd(const u16* __restrict__ Qhi, const u16* __restrict__ Qlo,
              const u16* __restrict__ Khi, const u16* __restrict__ Klo,
              const u16* __restrict__ Vt, u16* __restrict__ O) {
  const int blk = blockIdx.x;              // 512 blocks
  const int qb = blk & 15, bh = blk >> 4;
  const int h = bh & 15, b = bh >> 4;
  const int t0 = qb * 128;
  const int tid = threadIdx.x, wid = tid >> 6, lane = tid & 63;
  const int g = lane >> 4, l16 = lane & 15;
  const int par = g & 1;                   // group parity within 32-lane half
  const int hi2 = g >> 1;                  // which 32-lane half

  __shared__ __align__(16) u16 Ksh[2][64][64];   // keys x d (unpadded, swizzled)
  __shared__ __align__(16) u16 Ksl[2][64][64];
  __shared__ __align__(16) u16 Vs[2][64][64];    // d x keys (unpadded, swizzled)

  const int lrow = lane >> 3;              // 0..7
  const int lgc  = (lane & 7) ^ lrow;      // swizzled source granule
  const size_t kbase = (size_t)(b * 2048) * 1024 + h * 64;
  const size_t vbase = (size_t)(h * 64) * 4096 + b * 2048;

  auto issue_chunk = [&](int j0, int p) {
    const int row = wid * 8 + lrow;
    dma16(&Khi[kbase + (size_t)(j0 + row) * 1024 + lgc * 8], &Ksh[p][wid * 8][0]);
    dma16(&Klo[kbase + (size_t)(j0 + row) * 1024 + lgc * 8], &Ksl[p][wid * 8][0]);
    dma16(&Vt[vbase + (size_t)row * 4096 + j0 + lgc * 8],    &Vs[p][wid * 8][0]);
  };

  short8 qh[2], ql[2];
#pragma unroll
  for (int ks = 0; ks < 2; ++ks) {
    size_t qo = (size_t)(b * 2048 + t0 + wid * 16 + l16) * 1024
                + h * 64 + ks * 32 + g * 8;
    qh[ks] = *(const short8*)&Qhi[qo];
    ql[ks] = *(const short8*)&Qlo[qo];
  }

  float mrow = -1.0e30f;
  const f32x4 zero4 = {0.f, 0.f, 0.f, 0.f};
  f32x4 acc[5];                            // O^T quadrants; [4] = row-sum
#pragma unroll
  for (int dn = 0; dn < 5; ++dn) acc[dn] = zero4;

  short8 ones8;
#pragma unroll
  for (int j = 0; j < 8; ++j) ones8[j] = (short)0x3f80;   // bf16 1.0

  union PB { u32 w[4]; short8 v; };

  issue_chunk(0, 0);   // prologue DMA

  for (int i = 0; i < 32; ++i) {
    const int p = i & 1;
    __syncthreads();
    if (i < 31) issue_chunk((i + 1) * 64, 1 - p);

    f32x4 s[4];
#pragma unroll
    for (int n = 0; n < 4; ++n) s[n] = zero4;
#pragma unroll
    for (int ks = 0; ks < 2; ++ks)
#pragma unroll
      for (int n = 0; n < 4; ++n) {
        int col = (((ks * 4 + g) ^ (l16 & 7))) * 8;
        short8 kh = *(const short8*)&Ksh[p][n * 16 + l16][col];
        short8 kl = *(const short8*)&Ksl[p][n * 16 + l16][col];
        s[n] = __builtin_amdgcn_mfma_f32_16x16x32_bf16(kh, qh[ks], s[n], 0, 0, 0);
        s[n] = __builtin_amdgcn_mfma_f32_16x16x32_bf16(kh, ql[ks], s[n], 0, 0, 0);
        s[n] = __builtin_amdgcn_mfma_f32_16x16x32_bf16(kl, qh[ks], s[n], 0, 0, 0);
      }

    float cm = -1.0e30f;
#pragma unroll
    for (int n = 0; n < 4; ++n)
#pragma unroll
      for (int r = 0; r < 4; ++r) cm = fmaxf(cm, s[n][r]);
    cm = fmaxf(cm, __shfl_xor(cm, 16));
    cm = fmaxf(cm, __shfl_xor(cm, 32));
    if (!__all(cm <= mrow + 8.0f)) {
      float mnew = fmaxf(mrow, cm);
      float al = EXP2F(mrow - mnew);
      mrow = mnew;
#pragma unroll
      for (int dn = 0; dn < 5; ++dn)
#pragma unroll
        for (int r = 0; r < 4; ++r) acc[dn][r] *= al;
    }

    u32 pk[4][2];
#pragma unroll
    for (int n = 0; n < 4; ++n) {
      float p0 = EXP2F(s[n][0] - mrow);
      float p1 = EXP2F(s[n][1] - mrow);
      float p2 = EXP2F(s[n][2] - mrow);
      float p3 = EXP2F(s[n][3] - mrow);
      pk[n][0] = pack_hi16(__float_as_uint(p0), __float_as_uint(p1));
      pk[n][1] = pack_hi16(__float_as_uint(p2), __float_as_uint(p3));
    }
    PB pb[2];
#pragma unroll
    for (int ks2 = 0; ks2 < 2; ++ks2)
#pragma unroll
      for (int t = 0; t < 4; ++t) {
        int src = (((par << 1) | (t >> 1)) << 4) | l16;
        u32 w0 = (u32)__shfl((int)pk[2 * ks2][t & 1], src);
        u32 w1 = (u32)__shfl((int)pk[2 * ks2 + 1][t & 1], src);
        pb[ks2].w[t] = hi2 ? w1 : w0;
      }

#pragma unroll
    for (int ks2 = 0; ks2 < 2; ++ks2) {
#pragma unroll
      for (int dn = 0; dn < 4; ++dn) {
        int col = (((ks2 * 4 + g) ^ (l16 & 7))) * 8;
        short8 vb = *(const short8*)&Vs[p][dn * 16 + l16][col];
        acc[dn] = __builtin_amdgcn_mfma_f32_16x16x32_bf16(vb, pb[ks2].v, acc[dn], 0, 0, 0);
      }
      acc[4] = __builtin_amdgcn_mfma_f32_16x16x32_bf16(ones8, pb[ks2].v, acc[4], 0, 0, 0);
    }
  }

  float inv = 1.f / acc[4][0];
  int qrow = t0 + wid * 16 + l16;
  size_t base = (size_t)(b * 2048 + qrow) * 1024 + h * 64;
#pragma unroll
  for (int dn = 0; dn < 4; ++dn) {
    u32 o0 = pack_hi16(__float_as_uint(acc[dn][0] * inv),
                       __float_as_uint(acc[dn][1] * inv));
    u32 o1 = pack_hi16(__float_as_uint(acc[dn][2] * inv),
                       __float_as_uint(acc[dn][3] * inv));
    uint2 ov; ov.x = o0; ov.y = o1;
    *(uint2*)&O[base + dn * 16 + g * 4] = ov;
  }
}

// ---------------------------------------------------------------------------
extern "C" void kernel_launch(void* const* d_in, const int* in_sizes, int n_in,
                              void* d_out, int out_size, void* d_ws, size_t ws_size,
                              hipStream_t stream) {
  const float* x     = (const float*)d_in[0];
  const float* tx    = (const float*)d_in[1];
  const float* Wqkv  = (const float*)d_in[2];
  const float* Wtqkv = (const float*)d_in[3];
  const float* Wout  = (const float*)d_in[4];
  float* out = (float*)d_out;

  // workspace (peak 52 MB):
  //  0 Wtq_hi | 2 Wtq_lo | 4 Wk_hi | 6 Wk_lo | 8 Wv_hi | 10 Wout_b  (MB)
  //  12 Qhi 8 | 20 Qlo 8 | 28 Khi 8 | 36 Klo 8 | 44 Vt 8
  //  Ob (8MB) aliases 0-8 (weight planes dead after projections)
  char* ws = (char*)d_ws;
  const size_t MB = 1048576;
  u16* Wtq_hi = (u16*)(ws + 0 * MB);
  u16* Wtq_lo = (u16*)(ws + 2 * MB);
  u16* Wk_hi  = (u16*)(ws + 4 * MB);
  u16* Wk_lo  = (u16*)(ws + 6 * MB);
  u16* Wv_hi  = (u16*)(ws + 8 * MB);
  u16* Woutb  = (u16*)(ws + 10 * MB);
  u16* Qhi    = (u16*)(ws + 12 * MB);
  u16* Qlo    = (u16*)(ws + 20 * MB);
  u16* Khi    = (u16*)(ws + 28 * MB);
  u16* Klo    = (u16*)(ws + 36 * MB);
  u16* Vt     = (u16*)(ws + 44 * MB);
  u16* Ob     = (u16*)(ws + 0 * MB);
  if (ws_size < 52 * MB) return;

  const float QSCALE = 8.0f * 1.4426950408889634f;  // sqrt(d)=8, log2(e)

  repack_w<<<4096, 256, 0, stream>>>(Wqkv, Wtqkv, Wout,
                                     Wtq_hi, Wtq_lo, Wk_hi, Wk_lo, Wv_hi, Woutb);
  proj_fused<<<dim3(256, 3), 256, 0, stream>>>(x, tx, Wtq_hi, Wtq_lo, Wk_hi, Wk_lo,
                                               Wv_hi, Qhi, Qlo, Khi, Klo, Vt, QSCALE);
  attn_fwd<<<512, 512, 0, stream>>>(Qhi, Qlo, Khi, Klo, Vt, Ob);
  gemm_out<<<dim3(16, 32), 256, 0, stream>>>(Ob, Woutb, out, 4096, 1024, 1024);
}

// Round 9
// 289.779 us; speedup vs baseline: 1.4662x; 1.4662x over previous
//
#include <hip/hip_runtime.h>

// Inputs/outputs FLOAT32 per the reference. bf16 internally for MFMA (raw u16).
// r16: REVERT to the best-measured config (round-4 = 304.65us: proj v2 128x128
// F-through-LDS + attn v10 8-wave) after four proj restructures all regressed
// (r12 64x128 tile: 106us; r13 triple-buf+vmcnt: 126; r14 F-direct: 160;
// r15 F-reg-prefetch: 220 w/ scratch spills). r8/v2 proj is a robust local
// optimum. ONE new change this round: gemm_out ported to the proven r8
// staging pattern -- global_load_lds double-buffer (3 dma16/wave/step, same
// verified XOR-granule swizzle pair), ONE barrier/K-step, unpadded rows.
// Same A/B bits and MFMA order -> bit-identical output.
typedef unsigned short u16;
typedef unsigned int u32;
typedef __attribute__((ext_vector_type(8))) short short8;   // MFMA A/B frag
typedef __attribute__((ext_vector_type(4))) float f32x4;    // MFMA C/D frag

__device__ inline u16 f32_to_bf16(float f) {          // RNE (cold paths only)
  u32 u = __float_as_uint(f);
  u += 0x7fffu + ((u >> 16) & 1u);
  return (u16)(u >> 16);
}
__device__ inline float bf16_to_f32(u16 s) {
  return __uint_as_float(((u32)s) << 16);
}

#if __has_builtin(__builtin_amdgcn_exp2f)
#define EXP2F(x) __builtin_amdgcn_exp2f(x)
#else
#define EXP2F(x) exp2f(x)
#endif

// async 16B global->LDS DMA (dest = wave-uniform LDS base + lane*16)
__device__ inline void dma16(const void* gp, void* lp) {
  __builtin_amdgcn_global_load_lds(
      (const __attribute__((address_space(1))) u32*)gp,
      (__attribute__((address_space(3))) u32*)lp, 16, 0, 0);
}

// pack top-16 of two f32 words: out = (hi16(b)<<16) | hi16(a)
__device__ inline u32 pack_hi16(u32 a, u32 b) {
  return __builtin_amdgcn_perm(b, a, 0x07060302u);
}
// 8 f32 -> bf16x8 via truncation
__device__ inline uint4 pack_bf16_8(const uint4 a, const uint4 b) {
  uint4 r;
  r.x = pack_hi16(a.x, a.y);
  r.y = pack_hi16(a.z, a.w);
  r.z = pack_hi16(b.x, b.y);
  r.w = pack_hi16(b.z, b.w);
  return r;
}
// 8 f32 -> hi/lo bf16 planes. hi=trunc; lo=trunc(v-hi) (v-hi exact, Sterbenz).
__device__ inline void split8(const uint4 a, const uint4 b, uint4& hi, uint4& lo) {
  u32 u[8] = {a.x, a.y, a.z, a.w, b.x, b.y, b.z, b.w};
  u32 l[8];
#pragma unroll
  for (int j = 0; j < 8; ++j)
    l[j] = __float_as_uint(__uint_as_float(u[j]) - __uint_as_float(u[j] & 0xffff0000u));
  hi.x = pack_hi16(u[0], u[1]); hi.y = pack_hi16(u[2], u[3]);
  hi.z = pack_hi16(u[4], u[5]); hi.w = pack_hi16(u[6], u[7]);
  lo.x = pack_hi16(l[0], l[1]); lo.y = pack_hi16(l[2], l[3]);
  lo.z = pack_hi16(l[4], l[5]); lo.w = pack_hi16(l[6], l[7]);
}

// ---------------------------------------------------------------------------
// Weight repack + f32 -> bf16 hi/lo planes (RNE; one-time). j = d*48 + k*16 + h.
__global__ void repack_w(const float* __restrict__ Wqkv, const float* __restrict__ Wtqkv,
                         const float* __restrict__ Wout,
                         u16* __restrict__ Wtq_hi, u16* __restrict__ Wtq_lo,
                         u16* __restrict__ Wk_hi,  u16* __restrict__ Wk_lo,
                         u16* __restrict__ Wv_hi,  u16* __restrict__ Woutb) {
  int r = blockIdx.x;              // 0..4095
  int part = r >> 10;
  int rr = r & 1023;
  int h = rr >> 6, d = rr & 63;
  const float* src;
  u16 *dh, *dl = nullptr;
  if (part == 0)      { src = Wtqkv + (size_t)(d * 48 + h) * 1024;      dh = Wtq_hi + (size_t)rr * 1024; dl = Wtq_lo + (size_t)rr * 1024; }
  else if (part == 1) { src = Wqkv  + (size_t)(d * 48 + 16 + h) * 1024; dh = Wk_hi  + (size_t)rr * 1024; dl = Wk_lo  + (size_t)rr * 1024; }
  else if (part == 2) { src = Wqkv  + (size_t)(d * 48 + 32 + h) * 1024; dh = Wv_hi  + (size_t)rr * 1024; }
  else                { src = Wout  + (size_t)rr * 1024;                dh = Woutb  + (size_t)rr * 1024; }
  int c = threadIdx.x * 4;
  f32x4 v = *(const f32x4*)&src[c];
  u32 hv[4], lv[4];
#pragma unroll
  for (int j = 0; j < 4; ++j) {
    u16 hb = f32_to_bf16(v[j]);
    hv[j] = hb;
    lv[j] = f32_to_bf16(v[j] - bf16_to_f32(hb));
  }
  uint2 ho; ho.x = hv[0] | (hv[1] << 16); ho.y = hv[2] | (hv[3] << 16);
  *(uint2*)&dh[c] = ho;
  if (dl) {
    uint2 lo; lo.x = lv[0] | (lv[1] << 16); lo.y = lv[2] | (lv[3] << 16);
    *(uint2*)&dl[c] = lo;
  }
}

// ---------------------------------------------------------------------------
// Fused projection GEMM v2 (round-4 best: 128x128 tile, F/H/L through LDS via
// global_load_lds, double-buffered, ONE barrier per K-step). grid (256,3).
__global__ __launch_bounds__(256) __attribute__((amdgpu_waves_per_eu(2)))
void proj_fused(const float* __restrict__ x, const float* __restrict__ tx,
                const u16* __restrict__ Wtq_hi, const u16* __restrict__ Wtq_lo,
                const u16* __restrict__ Wk_hi,  const u16* __restrict__ Wk_lo,
                const u16* __restrict__ Wv_hi,
                u16* __restrict__ Qhi, u16* __restrict__ Qlo,
                u16* __restrict__ Khi, u16* __restrict__ Klo,
                u16* __restrict__ Vt, float qscale) {
  __shared__ __align__(16) float Fs[2][128][32];
  __shared__ __align__(16) u16   Hs[2][128][32];
  __shared__ __align__(16) u16   Ls[2][128][32];
  const int tid = threadIdx.x;
  const int wid = tid >> 6, lane = tid & 63;
  const int g = lane >> 4, l16 = lane & 15;
  const int job = blockIdx.y;
  const int tile = blockIdx.x;
  const int wm = (wid & 1) * 64, wn = (wid >> 1) * 64;

  int m0, n0, N, frow0, hrow0;
  const float* Fsrc;
  const u16 *Hsrc;
  const u16 *Lsrc = nullptr;
  if (job == 0) {
    m0 = (tile >> 3) * 128; n0 = (tile & 7) * 128; N = 1024;
    Fsrc = tx; frow0 = m0; Hsrc = Wtq_hi; Lsrc = Wtq_lo; hrow0 = n0;
  } else if (job == 1) {
    m0 = (tile >> 3) * 128; n0 = (tile & 7) * 128; N = 1024;
    Fsrc = x; frow0 = m0; Hsrc = Wk_hi; Lsrc = Wk_lo; hrow0 = n0;
  } else {
    m0 = (tile >> 5) * 128; n0 = (tile & 31) * 128; N = 4096;
    Fsrc = x; frow0 = n0; Hsrc = Wv_hi; hrow0 = m0;
  }

  const int lrow8 = lane >> 3;
  const int gf = (lane & 7) ^ lrow8;                       // F src granule
  const int lrow4 = lane >> 2;
  const int gh = (lane & 3) ^ ((lrow4 ^ (lrow4 >> 2)) & 3); // H/L src granule

  auto issue_chunk = [&](int k0, int p) {
#pragma unroll
    for (int t = 0; t < 4; ++t) {
      int rb = wid * 32 + t * 8;
      dma16(&Fsrc[(size_t)(frow0 + rb + lrow8) * 1024 + k0 + gf * 4], &Fs[p][rb][0]);
    }
#pragma unroll
    for (int t = 0; t < 2; ++t) {
      int rb = wid * 32 + t * 16;
      size_t ro = (size_t)(hrow0 + rb + lrow4) * 1024 + k0 + gh * 8;
      dma16(&Hsrc[ro], &Hs[p][rb][0]);
      if (job != 2) dma16(&Lsrc[ro], &Ls[p][rb][0]);
    }
  };

  f32x4 acc[4][4];
  const f32x4 zero4 = {0.f, 0.f, 0.f, 0.f};
#pragma unroll
  for (int i = 0; i < 4; ++i)
#pragma unroll
    for (int j = 0; j < 4; ++j) acc[i][j] = zero4;

  const int sw8 = l16 & 7;
  const int sw4 = (l16 ^ (l16 >> 2)) & 3;

  issue_chunk(0, 0);

  for (int k0 = 0; k0 < 1024; k0 += 32) {
    const int p = (k0 >> 5) & 1;
    __syncthreads();
    if (k0 + 32 < 1024) issue_chunk(k0 + 32, p ^ 1);

    if (job != 2) {
      short8 ah[4], al[4], bh4[4], bl4[4];
#pragma unroll
      for (int mi = 0; mi < 4; ++mi) {
        const int R = wm + mi * 16 + l16;
        uint4 u0 = *(const uint4*)&Fs[p][R][((2 * g) ^ sw8) * 4];
        uint4 u1 = *(const uint4*)&Fs[p][R][((2 * g + 1) ^ sw8) * 4];
        uint4 hi, lo;
        split8(u0, u1, hi, lo);
        ah[mi] = *(short8*)&hi;
        al[mi] = *(short8*)&lo;
      }
#pragma unroll
      for (int ni = 0; ni < 4; ++ni) {
        const int R = wn + ni * 16 + l16;
        const int col = (g ^ sw4) * 8;
        bh4[ni] = *(const short8*)&Hs[p][R][col];
        bl4[ni] = *(const short8*)&Ls[p][R][col];
      }
#pragma unroll
      for (int mi = 0; mi < 4; ++mi)
#pragma unroll
        for (int ni = 0; ni < 4; ++ni) {
          acc[mi][ni] = __builtin_amdgcn_mfma_f32_16x16x32_bf16(ah[mi], bh4[ni], acc[mi][ni], 0, 0, 0);
          acc[mi][ni] = __builtin_amdgcn_mfma_f32_16x16x32_bf16(ah[mi], bl4[ni], acc[mi][ni], 0, 0, 0);
          acc[mi][ni] = __builtin_amdgcn_mfma_f32_16x16x32_bf16(al[mi], bh4[ni], acc[mi][ni], 0, 0, 0);
        }
    } else {
      short8 av[4], bx[4];
#pragma unroll
      for (int mi = 0; mi < 4; ++mi)
        av[mi] = *(const short8*)&Hs[p][wm + mi * 16 + l16][(g ^ sw4) * 8];
#pragma unroll
      for (int ni = 0; ni < 4; ++ni) {
        const int R = wn + ni * 16 + l16;
        uint4 u0 = *(const uint4*)&Fs[p][R][((2 * g) ^ sw8) * 4];
        uint4 u1 = *(const uint4*)&Fs[p][R][((2 * g + 1) ^ sw8) * 4];
        uint4 t = pack_bf16_8(u0, u1);
        bx[ni] = *(short8*)&t;
      }
#pragma unroll
      for (int mi = 0; mi < 4; ++mi)
#pragma unroll
        for (int ni = 0; ni < 4; ++ni)
          acc[mi][ni] = __builtin_amdgcn_mfma_f32_16x16x32_bf16(av[mi], bx[ni], acc[mi][ni], 0, 0, 0);
    }
  }

  u16* Chi = (job == 0) ? Qhi : ((job == 1) ? Khi : Vt);
  u16* Clo = (job == 0) ? Qlo : Klo;
  float scale = (job == 0) ? qscale : 1.0f;
#pragma unroll
  for (int mi = 0; mi < 4; ++mi)
#pragma unroll
    for (int ni = 0; ni < 4; ++ni) {
      int row = m0 + wm + mi * 16 + g * 4;
      int col = n0 + wn + ni * 16 + l16;
#pragma unroll
      for (int r = 0; r < 4; ++r) {
        float v = acc[mi][ni][r] * scale;
        size_t o = (size_t)(row + r) * N + col;
        u32 uv = __float_as_uint(v);
        if (job != 2) {
          Chi[o] = (u16)(uv >> 16);
          float lo = v - __uint_as_float(uv & 0xffff0000u);
          Clo[o] = (u16)(__float_as_uint(lo) >> 16);
        } else {
          Chi[o] = (u16)(uv >> 16);
        }
      }
    }
}

// ---------------------------------------------------------------------------
// Final projection v2: C(f32) = A bf16 * B^T bf16, r8-style staging.
// 128x64 tile, global_load_lds double-buffer (A 2 + B 1 dma16/wave/step),
// ONE barrier per K-step, unpadded swizzled rows. grid (16,32) = 512 blocks.
__global__ __launch_bounds__(256)
void gemm_out(const u16* __restrict__ A, const u16* __restrict__ B,
              float* __restrict__ C, int M, int N, int K) {
  __shared__ __align__(16) u16 As[2][128][32];
  __shared__ __align__(16) u16 Bs[2][64][32];
  const int tid = threadIdx.x;
  const int wid = tid >> 6, lane = tid & 63;
  const int g = lane >> 4, l16 = lane & 15;
  const int m0 = blockIdx.y * 128, n0 = blockIdx.x * 64;
  const int wm = (wid & 1) * 64, wn = (wid >> 1) * 32;

  // DMA lane geometry (proj H/L pattern): 4x16B granules per 64B row,
  // gran ^= (r^(r>>2))&3; one dma16 covers 16 rows.
  const int lrow4 = lane >> 2;
  const int gh = (lane & 3) ^ ((lrow4 ^ (lrow4 >> 2)) & 3);

  auto issue_chunk = [&](int k0, int p) {
#pragma unroll
    for (int t = 0; t < 2; ++t) {            // A: 128 rows, 16 rows/dma
      int rb = wid * 32 + t * 16;
      dma16(&A[(size_t)(m0 + rb + lrow4) * K + k0 + gh * 8], &As[p][rb][0]);
    }
    {                                         // B: 64 rows, 16 rows/dma
      int rb = wid * 16;
      dma16(&B[(size_t)(n0 + rb + lrow4) * K + k0 + gh * 8], &Bs[p][rb][0]);
    }
  };

  f32x4 acc[4][2];
  const f32x4 zero4 = {0.f, 0.f, 0.f, 0.f};
#pragma unroll
  for (int i = 0; i < 4; ++i)
#pragma unroll
    for (int j = 0; j < 2; ++j) acc[i][j] = zero4;

  const int sw4 = (l16 ^ (l16 >> 2)) & 3;     // read-side swizzle

  issue_chunk(0, 0);

  for (int k0 = 0; k0 < K; k0 += 32) {
    const int p = (k0 >> 5) & 1;
    // Barrier's implicit vmcnt(0) drain: DMA into buf p (issued last step)
    // complete; all waves done reading buf p^1, so it's free for next DMA.
    __syncthreads();
    if (k0 + 32 < K) issue_chunk(k0 + 32, p ^ 1);

    short8 af[4], bfr[2];
#pragma unroll
    for (int mi = 0; mi < 4; ++mi)
      af[mi] = *(const short8*)&As[p][wm + mi * 16 + l16][(g ^ sw4) * 8];
#pragma unroll
    for (int ni = 0; ni < 2; ++ni)
      bfr[ni] = *(const short8*)&Bs[p][wn + ni * 16 + l16][(g ^ sw4) * 8];
#pragma unroll
    for (int mi = 0; mi < 4; ++mi)
#pragma unroll
      for (int ni = 0; ni < 2; ++ni)
        acc[mi][ni] = __builtin_amdgcn_mfma_f32_16x16x32_bf16(af[mi], bfr[ni], acc[mi][ni], 0, 0, 0);
  }
#pragma unroll
  for (int mi = 0; mi < 4; ++mi)
#pragma unroll
    for (int ni = 0; ni < 2; ++ni) {
      int row = m0 + wm + mi * 16 + g * 4;
      int col = n0 + wn + ni * 16 + l16;
#pragma unroll
      for (int r = 0; r < 4; ++r)
        C[(size_t)(row + r) * N + col] = acc[mi][ni][r];
    }
}

// ---------------------------------------------------------------------------
// Flash attention v10 (round-4 best): 8 waves x 16 q rows, swapped QK^T,
// in-register softmax with defer-max, __shfl P^T redistribution, PV = V^T.P^T.
__global__ __launch_bounds__(512)
void attn_fwd(const u16* __restrict__ Qhi, const u16* __restrict__ Qlo,
              const u16* __restrict__ Khi, const u16* __restrict__ Klo,
              const u16* __restrict__ Vt, u16* __restrict__ O) {
  const int blk = blockIdx.x;              // 512 blocks
  const int qb = blk & 15, bh = blk >> 4;
  const int h = bh & 15, b = bh >> 4;
  const int t0 = qb * 128;
  const int tid = threadIdx.x, wid = tid >> 6, lane = tid & 63;
  const int g = lane >> 4, l16 = lane & 15;
  const int par = g & 1;                   // group parity within 32-lane half
  const int hi2 = g >> 1;                  // which 32-lane half

  __shared__ __align__(16) u16 Ksh[2][64][64];   // keys x d (unpadded, swizzled)
  __shared__ __align__(16) u16 Ksl[2][64][64];
  __shared__ __align__(16) u16 Vs[2][64][64];    // d x keys (unpadded, swizzled)

  const int lrow = lane >> 3;              // 0..7
  const int lgc  = (lane & 7) ^ lrow;      // swizzled source granule
  const size_t kbase = (size_t)(b * 2048) * 1024 + h * 64;
  const size_t vbase = (size_t)(h * 64) * 4096 + b * 2048;

  auto issue_chunk = [&](int j0, int p) {
    const int row = wid * 8 + lrow;
    dma16(&Khi[kbase + (size_t)(j0 + row) * 1024 + lgc * 8], &Ksh[p][wid * 8][0]);
    dma16(&Klo[kbase + (size_t)(j0 + row) * 1024 + lgc * 8], &Ksl[p][wid * 8][0]);
    dma16(&Vt[vbase + (size_t)row * 4096 + j0 + lgc * 8],    &Vs[p][wid * 8][0]);
  };

  short8 qh[2], ql[2];
#pragma unroll
  for (int ks = 0; ks < 2; ++ks) {
    size_t qo = (size_t)(b * 2048 + t0 + wid * 16 + l16) * 1024
                + h * 64 + ks * 32 + g * 8;
    qh[ks] = *(const short8*)&Qhi[qo];
    ql[ks] = *(const short8*)&Qlo[qo];
  }

  float mrow = -1.0e30f;
  const f32x4 zero4 = {0.f, 0.f, 0.f, 0.f};
  f32x4 acc[5];                            // O^T quadrants; [4] = row-sum
#pragma unroll
  for (int dn = 0; dn < 5; ++dn) acc[dn] = zero4;

  short8 ones8;
#pragma unroll
  for (int j = 0; j < 8; ++j) ones8[j] = (short)0x3f80;   // bf16 1.0

  union PB { u32 w[4]; short8 v; };

  issue_chunk(0, 0);   // prologue DMA

  for (int i = 0; i < 32; ++i) {
    const int p = i & 1;
    __syncthreads();
    if (i < 31) issue_chunk((i + 1) * 64, 1 - p);

    f32x4 s[4];
#pragma unroll
    for (int n = 0; n < 4; ++n) s[n] = zero4;
#pragma unroll
    for (int ks = 0; ks < 2; ++ks)
#pragma unroll
      for (int n = 0; n < 4; ++n) {
        int col = (((ks * 4 + g) ^ (l16 & 7))) * 8;
        short8 kh = *(const short8*)&Ksh[p][n * 16 + l16][col];
        short8 kl = *(const short8*)&Ksl[p][n * 16 + l16][col];
        s[n] = __builtin_amdgcn_mfma_f32_16x16x32_bf16(kh, qh[ks], s[n], 0, 0, 0);
        s[n] = __builtin_amdgcn_mfma_f32_16x16x32_bf16(kh, ql[ks], s[n], 0, 0, 0);
        s[n] = __builtin_amdgcn_mfma_f32_16x16x32_bf16(kl, qh[ks], s[n], 0, 0, 0);
      }

    float cm = -1.0e30f;
#pragma unroll
    for (int n = 0; n < 4; ++n)
#pragma unroll
      for (int r = 0; r < 4; ++r) cm = fmaxf(cm, s[n][r]);
    cm = fmaxf(cm, __shfl_xor(cm, 16));
    cm = fmaxf(cm, __shfl_xor(cm, 32));
    if (!__all(cm <= mrow + 8.0f)) {
      float mnew = fmaxf(mrow, cm);
      float al = EXP2F(mrow - mnew);
      mrow = mnew;
#pragma unroll
      for (int dn = 0; dn < 5; ++dn)
#pragma unroll
        for (int r = 0; r < 4; ++r) acc[dn][r] *= al;
    }

    u32 pk[4][2];
#pragma unroll
    for (int n = 0; n < 4; ++n) {
      float p0 = EXP2F(s[n][0] - mrow);
      float p1 = EXP2F(s[n][1] - mrow);
      float p2 = EXP2F(s[n][2] - mrow);
      float p3 = EXP2F(s[n][3] - mrow);
      pk[n][0] = pack_hi16(__float_as_uint(p0), __float_as_uint(p1));
      pk[n][1] = pack_hi16(__float_as_uint(p2), __float_as_uint(p3));
    }
    PB pb[2];
#pragma unroll
    for (int ks2 = 0; ks2 < 2; ++ks2)
#pragma unroll
      for (int t = 0; t < 4; ++t) {
        int src = (((par << 1) | (t >> 1)) << 4) | l16;
        u32 w0 = (u32)__shfl((int)pk[2 * ks2][t & 1], src);
        u32 w1 = (u32)__shfl((int)pk[2 * ks2 + 1][t & 1], src);
        pb[ks2].w[t] = hi2 ? w1 : w0;
      }

#pragma unroll
    for (int ks2 = 0; ks2 < 2; ++ks2) {
#pragma unroll
      for (int dn = 0; dn < 4; ++dn) {
        int col = (((ks2 * 4 + g) ^ (l16 & 7))) * 8;
        short8 vb = *(const short8*)&Vs[p][dn * 16 + l16][col];
        acc[dn] = __builtin_amdgcn_mfma_f32_16x16x32_bf16(vb, pb[ks2].v, acc[dn], 0, 0, 0);
      }
      acc[4] = __builtin_amdgcn_mfma_f32_16x16x32_bf16(ones8, pb[ks2].v, acc[4], 0, 0, 0);
    }
  }

  float inv = 1.f / acc[4][0];
  int qrow = t0 + wid * 16 + l16;
  size_t base = (size_t)(b * 2048 + qrow) * 1024 + h * 64;
#pragma unroll
  for (int dn = 0; dn < 4; ++dn) {
    u32 o0 = pack_hi16(__float_as_uint(acc[dn][0] * inv),
                       __float_as_uint(acc[dn][1] * inv));
    u32 o1 = pack_hi16(__float_as_uint(acc[dn][2] * inv),
                       __float_as_uint(acc[dn][3] * inv));
    uint2 ov; ov.x = o0; ov.y = o1;
    *(uint2*)&O[base + dn * 16 + g * 4] = ov;
  }
}

// ---------------------------------------------------------------------------
extern "C" void kernel_launch(void* const* d_in, const int* in_sizes, int n_in,
                              void* d_out, int out_size, void* d_ws, size_t ws_size,
                              hipStream_t stream) {
  const float* x     = (const float*)d_in[0];
  const float* tx    = (const float*)d_in[1];
  const float* Wqkv  = (const float*)d_in[2];
  const float* Wtqkv = (const float*)d_in[3];
  const float* Wout  = (const float*)d_in[4];
  float* out = (float*)d_out;

  // workspace (peak 52 MB):
  //  0 Wtq_hi | 2 Wtq_lo | 4 Wk_hi | 6 Wk_lo | 8 Wv_hi | 10 Wout_b  (MB)
  //  12 Qhi 8 | 20 Qlo 8 | 28 Khi 8 | 36 Klo 8 | 44 Vt 8
  //  Ob (8MB) aliases 0-8 (weight planes dead after projections)
  char* ws = (char*)d_ws;
  const size_t MB = 1048576;
  u16* Wtq_hi = (u16*)(ws + 0 * MB);
  u16* Wtq_lo = (u16*)(ws + 2 * MB);
  u16* Wk_hi  = (u16*)(ws + 4 * MB);
  u16* Wk_lo  = (u16*)(ws + 6 * MB);
  u16* Wv_hi  = (u16*)(ws + 8 * MB);
  u16* Woutb  = (u16*)(ws + 10 * MB);
  u16* Qhi    = (u16*)(ws + 12 * MB);
  u16* Qlo    = (u16*)(ws + 20 * MB);
  u16* Khi    = (u16*)(ws + 28 * MB);
  u16* Klo    = (u16*)(ws + 36 * MB);
  u16* Vt     = (u16*)(ws + 44 * MB);
  u16* Ob     = (u16*)(ws + 0 * MB);
  if (ws_size < 52 * MB) return;

  const float QSCALE = 8.0f * 1.4426950408889634f;  // sqrt(d)=8, log2(e)

  repack_w<<<4096, 256, 0, stream>>>(Wqkv, Wtqkv, Wout,
                                     Wtq_hi, Wtq_lo, Wk_hi, Wk_lo, Wv_hi, Woutb);
  proj_fused<<<dim3(256, 3), 256, 0, stream>>>(x, tx, Wtq_hi, Wtq_lo, Wk_hi, Wk_lo,
                                               Wv_hi, Qhi, Qlo, Khi, Klo, Vt, QSCALE);
  attn_fwd<<<512, 512, 0, stream>>>(Qhi, Qlo, Khi, Klo, Vt, Ob);
  gemm_out<<<dim3(16, 32), 256, 0, stream>>>(Ob, Woutb, out, 4096, 1024, 1024);
}